// Round 4
// baseline (359.087 us; speedup 1.0000x reference)
//
#include <hip/hip_runtime.h>

typedef unsigned short u16;
typedef __bf16 bf16x8 __attribute__((ext_vector_type(8)));
typedef float f32x4 __attribute__((ext_vector_type(4)));
typedef unsigned short u16x8 __attribute__((ext_vector_type(8)));

__device__ __forceinline__ u16 f2bf(float f) {
  unsigned u = __builtin_bit_cast(unsigned, f);
  u += 0x7fffu + ((u >> 16) & 1u);
  return (u16)(u >> 16);
}
__device__ __forceinline__ float b2f(u16 h) {
  return __builtin_bit_cast(float, (unsigned)h << 16);
}

__device__ __forceinline__ void async16(const void* g, void* l) {
  __builtin_amdgcn_global_load_lds((const __attribute__((address_space(1))) void*)g,
                                   (__attribute__((address_space(3))) void*)l, 16, 0, 0);
}

// ---------------------------------------------------------------------------
// Weight conversion: q_w (scaled by C^-0.5) + k_w -> wqk [1024,512] bf16,
// v_w -> wv, p_w -> wp. blockIdx.y==4 builds the combined qk bias (f32).
// ---------------------------------------------------------------------------
__global__ __launch_bounds__(256) void cvt_kernel(const float* __restrict__ qw, const float* __restrict__ kw,
                                                  const float* __restrict__ vw, const float* __restrict__ pw,
                                                  const float* __restrict__ qb, const float* __restrict__ kb,
                                                  u16* __restrict__ wqk, u16* __restrict__ wv,
                                                  u16* __restrict__ wp, float* __restrict__ qkb,
                                                  float scale) {
  if (blockIdx.y == 4) {
    int i = blockIdx.x * 256 + threadIdx.x;
    if (i < 512) qkb[i] = qb[i] * scale;
    else if (i < 1024) qkb[i] = kb[i - 512];
    return;
  }
  const float* s;
  u16* o;
  float sc = 1.f;
  switch (blockIdx.y) {
    case 0: s = qw; o = wqk; sc = scale; break;
    case 1: s = kw; o = wqk + 262144; break;
    case 2: s = vw; o = wv; break;
    default: s = pw; o = wp; break;
  }
  int i = (blockIdx.x * 256 + threadIdx.x) * 4;
  float4 v = *(const float4*)(s + i);
  ushort4 pk = { f2bf(v.x * sc), f2bf(v.y * sc), f2bf(v.z * sc), f2bf(v.w * sc) };
  *(ushort4*)&o[i] = pk;
}

// ---------------------------------------------------------------------------
// GroupNorm: x [B,512,1024] f32 -> hn [B,1024,512] bf16 (transposed, k-contig)
// ---------------------------------------------------------------------------
#define GN_ROW 1026  // 1024 + 2 pad (odd word stride -> conflict-free)

__global__ __launch_bounds__(256) void gn_kernel(const float* __restrict__ x, const float* __restrict__ w,
                                                 const float* __restrict__ bias, u16* __restrict__ hn) {
  __shared__ u16 tile[16 * GN_ROW];
  __shared__ float red[18];
  const int tid = threadIdx.x;
  const int bb = blockIdx.x >> 5;
  const int g = blockIdx.x & 31;
  const float4* xb = (const float4*)(x + ((size_t)bb * 512 + (size_t)g * 16) * 1024);

  float s = 0.f, sq = 0.f;
#pragma unroll
  for (int j = 0; j < 16; ++j) {
    float4 v = xb[j * 256 + tid];
    s += v.x + v.y + v.z + v.w;
    sq += v.x * v.x + v.y * v.y + v.z * v.z + v.w * v.w;
    int base = j * GN_ROW + tid * 4;
    ushort2 p0 = { f2bf(v.x), f2bf(v.y) };
    ushort2 p1 = { f2bf(v.z), f2bf(v.w) };
    *(ushort2*)&tile[base] = p0;
    *(ushort2*)&tile[base + 2] = p1;
  }
#pragma unroll
  for (int o = 32; o; o >>= 1) {
    s += __shfl_down(s, o, 64);
    sq += __shfl_down(sq, o, 64);
  }
  const int wv = tid >> 6;
  if ((tid & 63) == 0) { red[wv] = s; red[wv + 4] = sq; }
  __syncthreads();
  if (tid == 0) {
    float S = red[0] + red[1] + red[2] + red[3];
    float Q = red[4] + red[5] + red[6] + red[7];
    float mean = S * (1.f / 16384.f);
    float var = Q * (1.f / 16384.f) - mean * mean;
    red[16] = mean;
    red[17] = rsqrtf(var + 1e-5f);
  }
  __syncthreads();
  const float mean = red[16], rstd = red[17];
  const int c0 = g * 16;

  float wf[16], bf_[16];
#pragma unroll
  for (int c = 0; c < 16; ++c) {
    float wc = w[c0 + c];
    wf[c] = wc * rstd;
    bf_[c] = bias[c0 + c] - mean * rstd * wc;
  }
#pragma unroll
  for (int it = 0; it < 4; ++it) {
    int hw = it * 256 + tid;
    u16x8 lo{}, hi{};
#pragma unroll
    for (int c = 0; c < 8; ++c) {
      lo[c] = f2bf(b2f(tile[c * GN_ROW + hw]) * wf[c] + bf_[c]);
      hi[c] = f2bf(b2f(tile[(c + 8) * GN_ROW + hw]) * wf[c + 8] + bf_[c + 8]);
    }
    u16* dst = hn + ((size_t)bb * 1024 + hw) * 512 + c0;
    *(u16x8*)dst = lo;
    *(u16x8*)(dst + 8) = hi;
  }
}

// ---------------------------------------------------------------------------
// NT GEMM: D[m,n] = sum_k A[m,k]*Bt[n,k] + bias_m[m] + bias_n[n] + res[m,n]
// BMxBN tile, BK=64, 512 threads = 8 waves laid out (8/WGN)xWGN, each wave
// a 64x(BN/WGN) subtile. mfma 16x16x32 bf16. XOR-swizzled conflict-free LDS.
// XCD swizzle: all tiles of batch z on XCD z%8 (per-XCD L2 working set).
// Non-temporal epilogue stores keep streaming output from thrashing L2.
// ---------------------------------------------------------------------------
template <int BM, int BN, int WGN, typename OutT>
__global__ __launch_bounds__(512, 2) void gemm_nt(const u16* __restrict__ A, const u16* __restrict__ Bt,
                                                  OutT* __restrict__ C, const float* __restrict__ bias_m,
                                                  const float* __restrict__ bias_n, const float* __restrict__ res,
                                                  int K, int lda, int ldb, int ldc,
                                                  size_t sA, size_t sB, size_t sC, size_t sRes,
                                                  int T, int lognbx) {
  constexpr int WGM = 8 / WGN;
  constexpr int SUBN = BN / WGN;          // 128 or 64
  constexpr int NT = SUBN / 16;           // 8 or 4
  constexpr int AIT = BM * 8 / 512;       // staging slots per thread (A)
  constexpr int BIT = BN * 8 / 512;
  __shared__ u16 lsA[BM * 64];
  __shared__ u16 lsB[BN * 64];

  // --- XCD-swizzle decode ---
  int fi = blockIdx.x;
  const int halfT = T << 3;
  const int h = (fi >= halfT);
  fi -= h * halfT;
  const int tile = fi >> 3;
  const int zb = (fi & 7) + (h << 3);
  const int bx = tile & ((1 << lognbx) - 1);
  const int by = tile >> lognbx;

  const int tid = threadIdx.x;
  const int lane = tid & 63;
  const int wave = tid >> 6;
  const int wm = wave / WGN, wn = wave % WGN;
  const int tm = by * BM, tn = bx * BN;
  const u16* Ab = A + (size_t)zb * sA;
  const u16* Bb = Bt + (size_t)zb * sB;

  f32x4 acc[4][NT] = {};
  const int q = lane >> 4, r = lane & 15;

  // staging map: slot e: row=e>>3, ch=e&7, global chunk = ch^(row&7)
  int arow[AIT], ach[AIT], brow[BIT], bch[BIT];
#pragma unroll
  for (int i = 0; i < AIT; ++i) {
    int e = tid + i * 512;
    arow[i] = e >> 3;
    ach[i] = (e & 7) ^ (arow[i] & 7);
  }
#pragma unroll
  for (int i = 0; i < BIT; ++i) {
    int e = tid + i * 512;
    brow[i] = e >> 3;
    bch[i] = (e & 7) ^ (brow[i] & 7);
  }

  for (int k0 = 0; k0 < K; k0 += 64) {
    __syncthreads();
#pragma unroll
    for (int i = 0; i < AIT; ++i)
      async16(Ab + (size_t)(tm + arow[i]) * lda + k0 + ach[i] * 8, (char*)lsA + (tid + i * 512) * 16);
#pragma unroll
    for (int i = 0; i < BIT; ++i)
      async16(Bb + (size_t)(tn + brow[i]) * ldb + k0 + bch[i] * 8, (char*)lsB + (tid + i * 512) * 16);
    __syncthreads();

#pragma unroll
    for (int kk = 0; kk < 2; ++kk) {
      bf16x8 af[4], bfv[NT];
#pragma unroll
      for (int mt = 0; mt < 4; ++mt) {
        int row = wm * 64 + mt * 16 + r;
        int chunk = (kk * 4 + q) ^ (row & 7);
        af[mt] = *(const bf16x8*)(const void*)&lsA[row * 64 + chunk * 8];
      }
#pragma unroll
      for (int nt = 0; nt < NT; ++nt) {
        int row = wn * SUBN + nt * 16 + r;
        int chunk = (kk * 4 + q) ^ (row & 7);
        bfv[nt] = *(const bf16x8*)(const void*)&lsB[row * 64 + chunk * 8];
      }
#pragma unroll
      for (int mt = 0; mt < 4; ++mt)
#pragma unroll
        for (int nt = 0; nt < NT; ++nt)
          acc[mt][nt] = __builtin_amdgcn_mfma_f32_16x16x32_bf16(af[mt], bfv[nt], acc[mt][nt], 0, 0, 0);
    }
  }

  OutT* Cb = C + (size_t)zb * sC;
  const float* Rb = res ? res + (size_t)zb * sRes : nullptr;
#pragma unroll
  for (int mt = 0; mt < 4; ++mt) {
#pragma unroll
    for (int nt = 0; nt < NT; ++nt) {
      const int col = tn + wn * SUBN + nt * 16 + r;
      const float bn = bias_n ? bias_n[col] : 0.f;
#pragma unroll
      for (int reg = 0; reg < 4; ++reg) {
        const int row = tm + wm * 64 + mt * 16 + q * 4 + reg;
        float v = acc[mt][nt][reg];
        const float bm = bias_m ? bias_m[row] : 0.f;
        v = v + bm + bn;
        const size_t idx = (size_t)row * ldc + col;
        if (Rb) v += __builtin_nontemporal_load(&Rb[idx]);
        if constexpr (__is_same(OutT, u16)) __builtin_nontemporal_store(f2bf(v), &Cb[idx]);
        else __builtin_nontemporal_store(v, &Cb[idx]);
      }
    }
  }
}

// ---------------------------------------------------------------------------
// Row softmax, in place on bf16 [rows,1024]; one wave per row, no barriers.
// ---------------------------------------------------------------------------
__global__ __launch_bounds__(256) void softmax_kernel(u16* __restrict__ S) {
  const int row = blockIdx.x * 4 + (threadIdx.x >> 6);
  const int lane = threadIdx.x & 63;
  u16* p = S + (size_t)row * 1024;
  u16x8 a = *(const u16x8*)(p + lane * 8);
  u16x8 b = *(const u16x8*)(p + 512 + lane * 8);
  float va[8], vb[8];
  float m = -3.0e38f;
#pragma unroll
  for (int j = 0; j < 8; ++j) {
    va[j] = b2f(a[j]);
    vb[j] = b2f(b[j]);
    m = fmaxf(m, fmaxf(va[j], vb[j]));
  }
#pragma unroll
  for (int o = 32; o; o >>= 1) m = fmaxf(m, __shfl_xor(m, o, 64));
  float s = 0.f;
#pragma unroll
  for (int j = 0; j < 8; ++j) {
    va[j] = __expf(va[j] - m);
    vb[j] = __expf(vb[j] - m);
    s += va[j] + vb[j];
  }
#pragma unroll
  for (int o = 32; o; o >>= 1) s += __shfl_xor(s, o, 64);
  const float inv = 1.f / s;
  u16x8 oa, ob;
#pragma unroll
  for (int j = 0; j < 8; ++j) {
    oa[j] = f2bf(va[j] * inv);
    ob[j] = f2bf(vb[j] * inv);
  }
  *(u16x8*)(p + lane * 8) = oa;
  *(u16x8*)(p + 512 + lane * 8) = ob;
}

// ---------------------------------------------------------------------------
extern "C" void kernel_launch(void* const* d_in, const int* in_sizes, int n_in,
                              void* d_out, int out_size, void* d_ws, size_t ws_size,
                              hipStream_t stream) {
  const float* x = (const float*)d_in[0];
  const float* gn_w = (const float*)d_in[2];
  const float* gn_b = (const float*)d_in[3];
  const float* q_w = (const float*)d_in[4];
  const float* q_b = (const float*)d_in[5];
  const float* k_w = (const float*)d_in[6];
  const float* k_b = (const float*)d_in[7];
  const float* v_w = (const float*)d_in[8];
  const float* v_b = (const float*)d_in[9];
  const float* p_w = (const float*)d_in[10];
  const float* p_b = (const float*)d_in[11];
  float* out = (float*)d_out;

  // workspace layout (u16 elements)
  u16* wqk = (u16*)d_ws;               // [1024,512]  (q scaled | k)
  u16* wv = wqk + 524288;              // [512,512]
  u16* wp = wv + 262144;               // [512,512]
  float* qkb = (float*)(wp + 262144);  // [1024] f32 combined bias
  u16* hn = wp + 262144 + 2048;        // [16,1024,512]
  u16* qkt = hn + 8388608;             // [16,1024,1024]  Q^T (scaled) | K^T
  u16* vv = qkt + 16777216;            // [16,512,1024]   V
  u16* ot = vv + 8388608;              // [16,1024,512]   O^T
  u16* Sb = ot + 8388608;              // [16,1024,1024]  scores / probs

  const float inv_sqrt_c = 0.044194173824159216f;  // 512^-0.5
  const size_t sHN = 524288, sS = 1048576;

  cvt_kernel<<<dim3(256, 5), 256, 0, stream>>>(q_w, k_w, v_w, p_w, q_b, k_b, wqk, wv, wp, qkb, inv_sqrt_c);
  gn_kernel<<<512, 256, 0, stream>>>(x, gn_w, gn_b, hn);

  // QK^T[b] = Hn^T . [Wq';Wk]^T + qkb   [1024,1024]  256x256, 16 tiles
  gemm_nt<256, 256, 2, u16><<<256, 512, 0, stream>>>(hn, wqk, qkt, nullptr, qkb, nullptr,
                                                     512, 512, 512, 1024, sHN, 0, sS, 0, 16, 2);
  // V[b] = Wv . Hn + v_b                 [512,1024]  128x256, 16 tiles
  gemm_nt<128, 256, 4, u16><<<256, 512, 0, stream>>>(wv, hn, vv, v_b, nullptr, nullptr,
                                                     512, 512, 512, 1024, 0, sHN, sHN, 0, 16, 2);
  // S[b] = Q'^T . K                      [1024,1024] 256x256, 16 tiles
  gemm_nt<256, 256, 2, u16><<<256, 512, 0, stream>>>(qkt, qkt + 512, Sb, nullptr, nullptr, nullptr,
                                                     512, 1024, 1024, 1024, sS, sS, sS, 0, 16, 2);
  softmax_kernel<<<4096, 256, 0, stream>>>(Sb);
  // O^T[b] = P . V^T                     [1024,512]  128x256, 16 tiles
  gemm_nt<128, 256, 4, u16><<<256, 512, 0, stream>>>(Sb, vv, ot, nullptr, nullptr, nullptr,
                                                     1024, 1024, 1024, 512, sS, sHN, sHN, 0, 16, 1);
  // out[b] = Wp . O + p_b + x            [512,1024] f32  128x256, 16 tiles
  gemm_nt<128, 256, 4, float><<<256, 512, 0, stream>>>(wp, ot, out, p_b, nullptr, x,
                                                       512, 512, 512, 1024, 0, sHN, sHN, sHN, 16, 2);
}

// Round 5
// 265.143 us; speedup vs baseline: 1.3543x; 1.3543x over previous
//
#include <hip/hip_runtime.h>

typedef unsigned short u16;
typedef __bf16 bf16x8 __attribute__((ext_vector_type(8)));
typedef float f32x4 __attribute__((ext_vector_type(4)));
typedef unsigned short u16x8 __attribute__((ext_vector_type(8)));

__device__ __forceinline__ u16 f2bf(float f) {
  unsigned u = __builtin_bit_cast(unsigned, f);
  u += 0x7fffu + ((u >> 16) & 1u);
  return (u16)(u >> 16);
}
__device__ __forceinline__ float b2f(u16 h) {
  return __builtin_bit_cast(float, (unsigned)h << 16);
}

__device__ __forceinline__ void async16(const void* g, void* l) {
  __builtin_amdgcn_global_load_lds((const __attribute__((address_space(1))) void*)g,
                                   (__attribute__((address_space(3))) void*)l, 16, 0, 0);
}

// ---------------------------------------------------------------------------
// Weight conversion: q_w (scaled by C^-0.5) + k_w -> wqk [1024,512] bf16,
// v_w -> wv, p_w -> wp. blockIdx.y==4 builds the combined qk bias (f32).
// ---------------------------------------------------------------------------
__global__ __launch_bounds__(256) void cvt_kernel(const float* __restrict__ qw, const float* __restrict__ kw,
                                                  const float* __restrict__ vw, const float* __restrict__ pw,
                                                  const float* __restrict__ qb, const float* __restrict__ kb,
                                                  u16* __restrict__ wqk, u16* __restrict__ wv,
                                                  u16* __restrict__ wp, float* __restrict__ qkb,
                                                  float scale) {
  if (blockIdx.y == 4) {
    int i = blockIdx.x * 256 + threadIdx.x;
    if (i < 512) qkb[i] = qb[i] * scale;
    else if (i < 1024) qkb[i] = kb[i - 512];
    return;
  }
  const float* s;
  u16* o;
  float sc = 1.f;
  switch (blockIdx.y) {
    case 0: s = qw; o = wqk; sc = scale; break;
    case 1: s = kw; o = wqk + 262144; break;
    case 2: s = vw; o = wv; break;
    default: s = pw; o = wp; break;
  }
  int i = (blockIdx.x * 256 + threadIdx.x) * 4;
  float4 v = *(const float4*)(s + i);
  ushort4 pk = { f2bf(v.x * sc), f2bf(v.y * sc), f2bf(v.z * sc), f2bf(v.w * sc) };
  *(ushort4*)&o[i] = pk;
}

// ---------------------------------------------------------------------------
// GroupNorm: x [B,512,1024] f32 -> hn [B,1024,512] bf16 (transposed, k-contig)
// ---------------------------------------------------------------------------
#define GN_ROW 1026  // 1024 + 2 pad (odd word stride -> conflict-free)

__global__ __launch_bounds__(256) void gn_kernel(const float* __restrict__ x, const float* __restrict__ w,
                                                 const float* __restrict__ bias, u16* __restrict__ hn) {
  __shared__ u16 tile[16 * GN_ROW];
  __shared__ float red[18];
  const int tid = threadIdx.x;
  const int bb = blockIdx.x >> 5;
  const int g = blockIdx.x & 31;
  const float4* xb = (const float4*)(x + ((size_t)bb * 512 + (size_t)g * 16) * 1024);

  float s = 0.f, sq = 0.f;
#pragma unroll
  for (int j = 0; j < 16; ++j) {
    float4 v = xb[j * 256 + tid];
    s += v.x + v.y + v.z + v.w;
    sq += v.x * v.x + v.y * v.y + v.z * v.z + v.w * v.w;
    int base = j * GN_ROW + tid * 4;
    ushort2 p0 = { f2bf(v.x), f2bf(v.y) };
    ushort2 p1 = { f2bf(v.z), f2bf(v.w) };
    *(ushort2*)&tile[base] = p0;
    *(ushort2*)&tile[base + 2] = p1;
  }
#pragma unroll
  for (int o = 32; o; o >>= 1) {
    s += __shfl_down(s, o, 64);
    sq += __shfl_down(sq, o, 64);
  }
  const int wv = tid >> 6;
  if ((tid & 63) == 0) { red[wv] = s; red[wv + 4] = sq; }
  __syncthreads();
  if (tid == 0) {
    float S = red[0] + red[1] + red[2] + red[3];
    float Q = red[4] + red[5] + red[6] + red[7];
    float mean = S * (1.f / 16384.f);
    float var = Q * (1.f / 16384.f) - mean * mean;
    red[16] = mean;
    red[17] = rsqrtf(var + 1e-5f);
  }
  __syncthreads();
  const float mean = red[16], rstd = red[17];
  const int c0 = g * 16;

  float wf[16], bf_[16];
#pragma unroll
  for (int c = 0; c < 16; ++c) {
    float wc = w[c0 + c];
    wf[c] = wc * rstd;
    bf_[c] = bias[c0 + c] - mean * rstd * wc;
  }
#pragma unroll
  for (int it = 0; it < 4; ++it) {
    int hw = it * 256 + tid;
    u16x8 lo{}, hi{};
#pragma unroll
    for (int c = 0; c < 8; ++c) {
      lo[c] = f2bf(b2f(tile[c * GN_ROW + hw]) * wf[c] + bf_[c]);
      hi[c] = f2bf(b2f(tile[(c + 8) * GN_ROW + hw]) * wf[c + 8] + bf_[c + 8]);
    }
    u16* dst = hn + ((size_t)bb * 1024 + hw) * 512 + c0;
    *(u16x8*)dst = lo;
    *(u16x8*)(dst + 8) = hi;
  }
}

// ---------------------------------------------------------------------------
// NT GEMM: D[m,n] = sum_k A[m,k]*Bt[n,k] + bias_m[m] + bias_n[n] + res[m,n]
// 128x128 tile, BK=64, 256 threads (4 waves of 64x64), mfma 16x16x32 bf16.
// XOR-swizzled LDS (conflict-free, verified R2). XCD swizzle (verified R3).
// NEW (R5): double-buffered LDS + raw s_barrier pipeline. stage(k+1) issues
// into buf^1, then s_waitcnt vmcnt(8) waits only for tile k's 8 loads (the
// 8 just-issued stay in flight across the barrier — the hipBLASLt pattern),
// so the m97 vmcnt(0) drain never happens. Second s_barrier protects buf k
// from being overwritten by stage(k+2) while laggard waves still read it.
// ---------------------------------------------------------------------------
template <typename OutT>
__global__ __launch_bounds__(256) void gemm_nt(const u16* __restrict__ A, const u16* __restrict__ Bt,
                                               OutT* __restrict__ C, const float* __restrict__ bias_m,
                                               const float* __restrict__ bias_n, const float* __restrict__ res,
                                               int K, int lda, int ldb, int ldc,
                                               size_t sA, size_t sB, size_t sC, size_t sRes,
                                               int T, int lognbx) {
  __shared__ u16 lsA[2][128 * 64];
  __shared__ u16 lsB[2][128 * 64];
  // --- XCD-swizzle decode ---
  int fi = blockIdx.x;
  const int halfT = T << 3;
  const int h = (fi >= halfT);
  fi -= h * halfT;
  const int tile = fi >> 3;
  const int zb = (fi & 7) + (h << 3);
  const int bx = tile & ((1 << lognbx) - 1);
  const int by = tile >> lognbx;

  const int tid = threadIdx.x;
  const int lane = tid & 63;
  const int wave = tid >> 6;
  const int wm = wave >> 1, wn = wave & 1;
  const int tm = by * 128, tn = bx * 128;
  const u16* Ab = A + (size_t)zb * sA;
  const u16* Bb = Bt + (size_t)zb * sB;

  f32x4 acc[4][4] = {};
  const int q = lane >> 4, r = lane & 15;

  // staging map: slot e in [0,1024): row=e>>3, ch=e&7, global chunk = ch^(row&7)
  int srow[4], gch[4];
#pragma unroll
  for (int i = 0; i < 4; ++i) {
    int e = tid + i * 256;
    srow[i] = e >> 3;
    gch[i] = (e & 7) ^ (srow[i] & 7);
  }

  auto stage = [&](int k0, int db) {
#pragma unroll
    for (int i = 0; i < 4; ++i)
      async16(Ab + (size_t)(tm + srow[i]) * lda + k0 + gch[i] * 8, (char*)lsA[db] + (tid + i * 256) * 16);
#pragma unroll
    for (int i = 0; i < 4; ++i)
      async16(Bb + (size_t)(tn + srow[i]) * ldb + k0 + gch[i] * 8, (char*)lsB[db] + (tid + i * 256) * 16);
  };

  const int nk = K >> 6;
  stage(0, 0);
  for (int k = 0; k < nk; ++k) {
    const int cur = k & 1;
    if (k + 1 < nk) {
      stage((k + 1) << 6, cur ^ 1);
      asm volatile("s_waitcnt vmcnt(8)" ::: "memory");  // tile k landed; k+1 stays in flight
    } else {
      asm volatile("s_waitcnt vmcnt(0)" ::: "memory");
    }
    asm volatile("s_barrier" ::: "memory");

    const u16* As = lsA[cur];
    const u16* Bs = lsB[cur];
#pragma unroll
    for (int kk = 0; kk < 2; ++kk) {
      bf16x8 af[4], bfv[4];
#pragma unroll
      for (int mt = 0; mt < 4; ++mt) {
        int row = wm * 64 + mt * 16 + r;
        int chunk = (kk * 4 + q) ^ (row & 7);
        af[mt] = *(const bf16x8*)(const void*)&As[row * 64 + chunk * 8];
      }
#pragma unroll
      for (int nt = 0; nt < 4; ++nt) {
        int row = wn * 64 + nt * 16 + r;
        int chunk = (kk * 4 + q) ^ (row & 7);
        bfv[nt] = *(const bf16x8*)(const void*)&Bs[row * 64 + chunk * 8];
      }
#pragma unroll
      for (int mt = 0; mt < 4; ++mt)
#pragma unroll
        for (int nt = 0; nt < 4; ++nt)
          acc[mt][nt] = __builtin_amdgcn_mfma_f32_16x16x32_bf16(af[mt], bfv[nt], acc[mt][nt], 0, 0, 0);
    }
    asm volatile("s_barrier" ::: "memory");  // all waves done reading buf cur
  }

  OutT* Cb = C + (size_t)zb * sC;
  const float* Rb = res ? res + (size_t)zb * sRes : nullptr;
#pragma unroll
  for (int mt = 0; mt < 4; ++mt) {
#pragma unroll
    for (int nt = 0; nt < 4; ++nt) {
      const int col = tn + wn * 64 + nt * 16 + r;
      const float bn = bias_n ? bias_n[col] : 0.f;
#pragma unroll
      for (int reg = 0; reg < 4; ++reg) {
        const int row = tm + wm * 64 + mt * 16 + q * 4 + reg;
        float v = acc[mt][nt][reg];
        const float bm = bias_m ? bias_m[row] : 0.f;
        v = v + bm + bn;
        const size_t idx = (size_t)row * ldc + col;
        if (Rb) v += Rb[idx];
        if constexpr (__is_same(OutT, u16)) Cb[idx] = f2bf(v);
        else Cb[idx] = v;
      }
    }
  }
}

// ---------------------------------------------------------------------------
// Row softmax, in place on bf16 [rows,1024]; one wave per row, no barriers.
// ---------------------------------------------------------------------------
__global__ __launch_bounds__(256) void softmax_kernel(u16* __restrict__ S) {
  const int row = blockIdx.x * 4 + (threadIdx.x >> 6);
  const int lane = threadIdx.x & 63;
  u16* p = S + (size_t)row * 1024;
  u16x8 a = *(const u16x8*)(p + lane * 8);
  u16x8 b = *(const u16x8*)(p + 512 + lane * 8);
  float va[8], vb[8];
  float m = -3.0e38f;
#pragma unroll
  for (int j = 0; j < 8; ++j) {
    va[j] = b2f(a[j]);
    vb[j] = b2f(b[j]);
    m = fmaxf(m, fmaxf(va[j], vb[j]));
  }
#pragma unroll
  for (int o = 32; o; o >>= 1) m = fmaxf(m, __shfl_xor(m, o, 64));
  float s = 0.f;
#pragma unroll
  for (int j = 0; j < 8; ++j) {
    va[j] = __expf(va[j] - m);
    vb[j] = __expf(vb[j] - m);
    s += va[j] + vb[j];
  }
#pragma unroll
  for (int o = 32; o; o >>= 1) s += __shfl_xor(s, o, 64);
  const float inv = 1.f / s;
  u16x8 oa, ob;
#pragma unroll
  for (int j = 0; j < 8; ++j) {
    oa[j] = f2bf(va[j] * inv);
    ob[j] = f2bf(vb[j] * inv);
  }
  *(u16x8*)(p + lane * 8) = oa;
  *(u16x8*)(p + 512 + lane * 8) = ob;
}

// ---------------------------------------------------------------------------
extern "C" void kernel_launch(void* const* d_in, const int* in_sizes, int n_in,
                              void* d_out, int out_size, void* d_ws, size_t ws_size,
                              hipStream_t stream) {
  const float* x = (const float*)d_in[0];
  const float* gn_w = (const float*)d_in[2];
  const float* gn_b = (const float*)d_in[3];
  const float* q_w = (const float*)d_in[4];
  const float* q_b = (const float*)d_in[5];
  const float* k_w = (const float*)d_in[6];
  const float* k_b = (const float*)d_in[7];
  const float* v_w = (const float*)d_in[8];
  const float* v_b = (const float*)d_in[9];
  const float* p_w = (const float*)d_in[10];
  const float* p_b = (const float*)d_in[11];
  float* out = (float*)d_out;

  // workspace layout (u16 elements)
  u16* wqk = (u16*)d_ws;               // [1024,512]  (q scaled | k)
  u16* wv = wqk + 524288;              // [512,512]
  u16* wp = wv + 262144;               // [512,512]
  float* qkb = (float*)(wp + 262144);  // [1024] f32 combined bias
  u16* hn = wp + 262144 + 2048;        // [16,1024,512]
  u16* qkt = hn + 8388608;             // [16,1024,1024]  Q^T (scaled) | K^T
  u16* vv = qkt + 16777216;            // [16,512,1024]   V
  u16* ot = vv + 8388608;              // [16,1024,512]   O^T
  u16* Sb = ot + 8388608;              // [16,1024,1024]  scores / probs

  const float inv_sqrt_c = 0.044194173824159216f;  // 512^-0.5
  const size_t sHN = 524288, sS = 1048576;

  cvt_kernel<<<dim3(256, 5), 256, 0, stream>>>(q_w, k_w, v_w, p_w, q_b, k_b, wqk, wv, wp, qkb, inv_sqrt_c);
  gn_kernel<<<512, 256, 0, stream>>>(x, gn_w, gn_b, hn);

  // QK^T[b] = Hn^T . [Wq';Wk]^T + qkb   [1024,1024]   T=64 tiles (8x8), nbx=8
  gemm_nt<u16><<<dim3(16 * 64), 256, 0, stream>>>(hn, wqk, qkt, nullptr, qkb, nullptr,
                                                  512, 512, 512, 1024, sHN, 0, sS, 0, 64, 3);
  // V[b] = Wv . Hn + v_b                 [512,1024]   T=32 tiles (4x8), nbx=8
  gemm_nt<u16><<<dim3(16 * 32), 256, 0, stream>>>(wv, hn, vv, v_b, nullptr, nullptr,
                                                  512, 512, 512, 1024, 0, sHN, sHN, 0, 32, 3);
  // S[b] = Q'^T . K                      [1024,1024]  T=64 tiles (8x8), nbx=8
  gemm_nt<u16><<<dim3(16 * 64), 256, 0, stream>>>(qkt, qkt + 512, Sb, nullptr, nullptr, nullptr,
                                                  512, 1024, 1024, 1024, sS, sS, sS, 0, 64, 3);
  softmax_kernel<<<4096, 256, 0, stream>>>(Sb);
  // O^T[b] = P . V^T                     [1024,512]   T=32 tiles (8x4), nbx=4
  gemm_nt<u16><<<dim3(16 * 32), 256, 0, stream>>>(Sb, vv, ot, nullptr, nullptr, nullptr,
                                                  1024, 1024, 1024, 512, sS, sHN, sHN, 0, 32, 2);
  // out[b] = Wp . O + p_b + x            [512,1024] f32  T=32 tiles (4x8), nbx=8
  gemm_nt<float><<<dim3(16 * 32), 256, 0, stream>>>(wp, ot, out, p_b, nullptr, x,
                                                    512, 512, 512, 1024, 0, sHN, sHN, sHN, 32, 3);
}

// Round 6
// 264.546 us; speedup vs baseline: 1.3574x; 1.0023x over previous
//
#include <hip/hip_runtime.h>

typedef unsigned short u16;
typedef __bf16 bf16x8 __attribute__((ext_vector_type(8)));
typedef float f32x4 __attribute__((ext_vector_type(4)));
typedef unsigned short u16x8 __attribute__((ext_vector_type(8)));

__device__ __forceinline__ u16 f2bf(float f) {
  unsigned u = __builtin_bit_cast(unsigned, f);
  u += 0x7fffu + ((u >> 16) & 1u);
  return (u16)(u >> 16);
}
__device__ __forceinline__ float b2f(u16 h) {
  return __builtin_bit_cast(float, (unsigned)h << 16);
}

// ---------------------------------------------------------------------------
// Weight conversion: q_w (scaled by C^-0.5) + k_w -> wqk [1024,512] bf16,
// v_w -> wv, p_w -> wp. blockIdx.y==4 builds the combined qk bias (f32).
// ---------------------------------------------------------------------------
__global__ __launch_bounds__(256) void cvt_kernel(const float* __restrict__ qw, const float* __restrict__ kw,
                                                  const float* __restrict__ vw, const float* __restrict__ pw,
                                                  const float* __restrict__ qb, const float* __restrict__ kb,
                                                  u16* __restrict__ wqk, u16* __restrict__ wv,
                                                  u16* __restrict__ wp, float* __restrict__ qkb,
                                                  float scale) {
  if (blockIdx.y == 4) {
    int i = blockIdx.x * 256 + threadIdx.x;
    if (i < 512) qkb[i] = qb[i] * scale;
    else if (i < 1024) qkb[i] = kb[i - 512];
    return;
  }
  const float* s;
  u16* o;
  float sc = 1.f;
  switch (blockIdx.y) {
    case 0: s = qw; o = wqk; sc = scale; break;
    case 1: s = kw; o = wqk + 262144; break;
    case 2: s = vw; o = wv; break;
    default: s = pw; o = wp; break;
  }
  int i = (blockIdx.x * 256 + threadIdx.x) * 4;
  float4 v = *(const float4*)(s + i);
  ushort4 pk = { f2bf(v.x * sc), f2bf(v.y * sc), f2bf(v.z * sc), f2bf(v.w * sc) };
  *(ushort4*)&o[i] = pk;
}

// ---------------------------------------------------------------------------
// GroupNorm: x [B,512,1024] f32 -> hn [B,1024,512] bf16 (transposed, k-contig)
// ---------------------------------------------------------------------------
#define GN_ROW 1026  // 1024 + 2 pad (odd word stride -> conflict-free)

__global__ __launch_bounds__(256) void gn_kernel(const float* __restrict__ x, const float* __restrict__ w,
                                                 const float* __restrict__ bias, u16* __restrict__ hn) {
  __shared__ u16 tile[16 * GN_ROW];
  __shared__ float red[18];
  const int tid = threadIdx.x;
  const int bb = blockIdx.x >> 5;
  const int g = blockIdx.x & 31;
  const float4* xb = (const float4*)(x + ((size_t)bb * 512 + (size_t)g * 16) * 1024);

  float s = 0.f, sq = 0.f;
#pragma unroll
  for (int j = 0; j < 16; ++j) {
    float4 v = xb[j * 256 + tid];
    s += v.x + v.y + v.z + v.w;
    sq += v.x * v.x + v.y * v.y + v.z * v.z + v.w * v.w;
    int base = j * GN_ROW + tid * 4;
    ushort2 p0 = { f2bf(v.x), f2bf(v.y) };
    ushort2 p1 = { f2bf(v.z), f2bf(v.w) };
    *(ushort2*)&tile[base] = p0;
    *(ushort2*)&tile[base + 2] = p1;
  }
#pragma unroll
  for (int o = 32; o; o >>= 1) {
    s += __shfl_down(s, o, 64);
    sq += __shfl_down(sq, o, 64);
  }
  const int wv = tid >> 6;
  if ((tid & 63) == 0) { red[wv] = s; red[wv + 4] = sq; }
  __syncthreads();
  if (tid == 0) {
    float S = red[0] + red[1] + red[2] + red[3];
    float Q = red[4] + red[5] + red[6] + red[7];
    float mean = S * (1.f / 16384.f);
    float var = Q * (1.f / 16384.f) - mean * mean;
    red[16] = mean;
    red[17] = rsqrtf(var + 1e-5f);
  }
  __syncthreads();
  const float mean = red[16], rstd = red[17];
  const int c0 = g * 16;

  float wf[16], bf_[16];
#pragma unroll
  for (int c = 0; c < 16; ++c) {
    float wc = w[c0 + c];
    wf[c] = wc * rstd;
    bf_[c] = bias[c0 + c] - mean * rstd * wc;
  }
#pragma unroll
  for (int it = 0; it < 4; ++it) {
    int hw = it * 256 + tid;
    u16x8 lo{}, hi{};
#pragma unroll
    for (int c = 0; c < 8; ++c) {
      lo[c] = f2bf(b2f(tile[c * GN_ROW + hw]) * wf[c] + bf_[c]);
      hi[c] = f2bf(b2f(tile[(c + 8) * GN_ROW + hw]) * wf[c + 8] + bf_[c + 8]);
    }
    u16* dst = hn + ((size_t)bb * 1024 + hw) * 512 + c0;
    *(u16x8*)dst = lo;
    *(u16x8*)(dst + 8) = hi;
  }
}

// ---------------------------------------------------------------------------
// NT GEMM: D[m,n] = sum_k A[m,k]*Bt[n,k] + bias_m[m] + bias_n[n] + res[m,n]
// 128x128 tile, BK=32, 256 threads (4 waves of 64x64), mfma 16x16x32 bf16.
// R6: staging via buffer_load->VGPR->ds_write (hipBLASLt path), replacing
// global_load_lds (whose per-wave DMA queue capped staging at ~2 B/cyc/wave
// across R1/R3/R5). Double-buffered LDS; per iter: issue k+1 global loads,
// compute tile k (covers latency), ds_write k+1 (compiler emits exact vmcnt
// wait), one __syncthreads (vmcnt(0) free: no VMEM in flight at barrier).
// Swizzle slot = chunk ^ ((row>>1)&3): conflict-free for ds_write_b128 and
// ds_read_b128 (8 words/bank uniform). XCD swizzle kept (verified R3).
// ---------------------------------------------------------------------------
template <typename OutT>
__global__ __launch_bounds__(256, 3) void gemm_nt(const u16* __restrict__ A, const u16* __restrict__ Bt,
                                                  OutT* __restrict__ C, const float* __restrict__ bias_m,
                                                  const float* __restrict__ bias_n, const float* __restrict__ res,
                                                  int K, int lda, int ldb, int ldc,
                                                  size_t sA, size_t sB, size_t sC, size_t sRes,
                                                  int T, int lognbx) {
  __shared__ u16 lsA[2][128 * 32];
  __shared__ u16 lsB[2][128 * 32];
  // --- XCD-swizzle decode ---
  int fi = blockIdx.x;
  const int halfT = T << 3;
  const int h = (fi >= halfT);
  fi -= h * halfT;
  const int tile = fi >> 3;
  const int zb = (fi & 7) + (h << 3);
  const int bx = tile & ((1 << lognbx) - 1);
  const int by = tile >> lognbx;

  const int tid = threadIdx.x;
  const int lane = tid & 63;
  const int wave = tid >> 6;
  const int wm = wave >> 1, wn = wave & 1;
  const int tm = by * 128, tn = bx * 128;
  const u16* Ab = A + (size_t)zb * sA;
  const u16* Bb = Bt + (size_t)zb * sB;

  f32x4 acc[4][4] = {};
  const int q = lane >> 4, r = lane & 15;

  // staging: thread t handles rows ra, ra+64 and 16B chunk g (4 lanes share a
  // 64B line -> minimal 16 lines per wave-instruction).
  const int ra = tid >> 2;
  const int g = tid & 3;
  const int s0 = g ^ ((ra >> 1) & 3);            // swizzled slot, row ra
  const int s1 = g ^ (((ra + 64) >> 1) & 3);     // swizzled slot, row ra+64
  const u16* pa0 = Ab + (size_t)(tm + ra) * lda + g * 8;
  const u16* pa1 = Ab + (size_t)(tm + ra + 64) * lda + g * 8;
  const u16* pb0 = Bb + (size_t)(tn + ra) * ldb + g * 8;
  const u16* pb1 = Bb + (size_t)(tn + ra + 64) * ldb + g * 8;
  const int wa0 = ra * 32 + s0 * 8, wa1 = (ra + 64) * 32 + s1 * 8;

  u16x8 rA0, rA1, rB0, rB1;
  rA0 = *(const u16x8*)(pa0);
  rA1 = *(const u16x8*)(pa1);
  rB0 = *(const u16x8*)(pb0);
  rB1 = *(const u16x8*)(pb1);
  *(u16x8*)&lsA[0][wa0] = rA0;
  *(u16x8*)&lsA[0][wa1] = rA1;
  *(u16x8*)&lsB[0][wa0] = rB0;
  *(u16x8*)&lsB[0][wa1] = rB1;
  __syncthreads();

  // fragment read offsets (swizzled)
  int offA[4], offB[4];
#pragma unroll
  for (int mt = 0; mt < 4; ++mt) {
    int rowa = wm * 64 + mt * 16 + r;
    offA[mt] = rowa * 32 + (q ^ ((rowa >> 1) & 3)) * 8;
    int rowb = wn * 64 + mt * 16 + r;
    offB[mt] = rowb * 32 + (q ^ ((rowb >> 1) & 3)) * 8;
  }

  const int nk = K >> 5;
  for (int k = 0; k < nk; ++k) {
    const int cur = k & 1;
    if (k + 1 < nk) {
      const int k0 = (k + 1) << 5;
      rA0 = *(const u16x8*)(pa0 + k0);
      rA1 = *(const u16x8*)(pa1 + k0);
      rB0 = *(const u16x8*)(pb0 + k0);
      rB1 = *(const u16x8*)(pb1 + k0);
    }
    bf16x8 af[4], bfv[4];
#pragma unroll
    for (int mt = 0; mt < 4; ++mt) {
      af[mt] = *(const bf16x8*)(const void*)&lsA[cur][offA[mt]];
      bfv[mt] = *(const bf16x8*)(const void*)&lsB[cur][offB[mt]];
    }
#pragma unroll
    for (int mt = 0; mt < 4; ++mt)
#pragma unroll
      for (int nt = 0; nt < 4; ++nt)
        acc[mt][nt] = __builtin_amdgcn_mfma_f32_16x16x32_bf16(af[mt], bfv[nt], acc[mt][nt], 0, 0, 0);
    if (k + 1 < nk) {
      const int nxt = cur ^ 1;
      *(u16x8*)&lsA[nxt][wa0] = rA0;
      *(u16x8*)&lsA[nxt][wa1] = rA1;
      *(u16x8*)&lsB[nxt][wa0] = rB0;
      *(u16x8*)&lsB[nxt][wa1] = rB1;
    }
    __syncthreads();
  }

  OutT* Cb = C + (size_t)zb * sC;
  const float* Rb = res ? res + (size_t)zb * sRes : nullptr;
#pragma unroll
  for (int mt = 0; mt < 4; ++mt) {
#pragma unroll
    for (int nt = 0; nt < 4; ++nt) {
      const int col = tn + wn * 64 + nt * 16 + r;
      const float bn = bias_n ? bias_n[col] : 0.f;
#pragma unroll
      for (int reg = 0; reg < 4; ++reg) {
        const int row = tm + wm * 64 + mt * 16 + q * 4 + reg;
        float v = acc[mt][nt][reg];
        const float bm = bias_m ? bias_m[row] : 0.f;
        v = v + bm + bn;
        const size_t idx = (size_t)row * ldc + col;
        if (Rb) v += Rb[idx];
        if constexpr (__is_same(OutT, u16)) Cb[idx] = f2bf(v);
        else Cb[idx] = v;
      }
    }
  }
}

// ---------------------------------------------------------------------------
// Row softmax, in place on bf16 [rows,1024]; one wave per row, no barriers.
// ---------------------------------------------------------------------------
__global__ __launch_bounds__(256) void softmax_kernel(u16* __restrict__ S) {
  const int row = blockIdx.x * 4 + (threadIdx.x >> 6);
  const int lane = threadIdx.x & 63;
  u16* p = S + (size_t)row * 1024;
  u16x8 a = *(const u16x8*)(p + lane * 8);
  u16x8 b = *(const u16x8*)(p + 512 + lane * 8);
  float va[8], vb[8];
  float m = -3.0e38f;
#pragma unroll
  for (int j = 0; j < 8; ++j) {
    va[j] = b2f(a[j]);
    vb[j] = b2f(b[j]);
    m = fmaxf(m, fmaxf(va[j], vb[j]));
  }
#pragma unroll
  for (int o = 32; o; o >>= 1) m = fmaxf(m, __shfl_xor(m, o, 64));
  float s = 0.f;
#pragma unroll
  for (int j = 0; j < 8; ++j) {
    va[j] = __expf(va[j] - m);
    vb[j] = __expf(vb[j] - m);
    s += va[j] + vb[j];
  }
#pragma unroll
  for (int o = 32; o; o >>= 1) s += __shfl_xor(s, o, 64);
  const float inv = 1.f / s;
  u16x8 oa, ob;
#pragma unroll
  for (int j = 0; j < 8; ++j) {
    oa[j] = f2bf(va[j] * inv);
    ob[j] = f2bf(vb[j] * inv);
  }
  *(u16x8*)(p + lane * 8) = oa;
  *(u16x8*)(p + 512 + lane * 8) = ob;
}

// ---------------------------------------------------------------------------
extern "C" void kernel_launch(void* const* d_in, const int* in_sizes, int n_in,
                              void* d_out, int out_size, void* d_ws, size_t ws_size,
                              hipStream_t stream) {
  const float* x = (const float*)d_in[0];
  const float* gn_w = (const float*)d_in[2];
  const float* gn_b = (const float*)d_in[3];
  const float* q_w = (const float*)d_in[4];
  const float* q_b = (const float*)d_in[5];
  const float* k_w = (const float*)d_in[6];
  const float* k_b = (const float*)d_in[7];
  const float* v_w = (const float*)d_in[8];
  const float* v_b = (const float*)d_in[9];
  const float* p_w = (const float*)d_in[10];
  const float* p_b = (const float*)d_in[11];
  float* out = (float*)d_out;

  // workspace layout (u16 elements)
  u16* wqk = (u16*)d_ws;               // [1024,512]  (q scaled | k)
  u16* wv = wqk + 524288;              // [512,512]
  u16* wp = wv + 262144;               // [512,512]
  float* qkb = (float*)(wp + 262144);  // [1024] f32 combined bias
  u16* hn = wp + 262144 + 2048;        // [16,1024,512]
  u16* qkt = hn + 8388608;             // [16,1024,1024]  Q^T (scaled) | K^T
  u16* vv = qkt + 16777216;            // [16,512,1024]   V
  u16* ot = vv + 8388608;              // [16,1024,512]   O^T
  u16* Sb = ot + 8388608;              // [16,1024,1024]  scores / probs

  const float inv_sqrt_c = 0.044194173824159216f;  // 512^-0.5
  const size_t sHN = 524288, sS = 1048576;

  cvt_kernel<<<dim3(256, 5), 256, 0, stream>>>(q_w, k_w, v_w, p_w, q_b, k_b, wqk, wv, wp, qkb, inv_sqrt_c);
  gn_kernel<<<512, 256, 0, stream>>>(x, gn_w, gn_b, hn);

  // QK^T[b] = Hn^T . [Wq';Wk]^T + qkb   [1024,1024]   T=64 tiles (8x8), nbx=8
  gemm_nt<u16><<<dim3(16 * 64), 256, 0, stream>>>(hn, wqk, qkt, nullptr, qkb, nullptr,
                                                  512, 512, 512, 1024, sHN, 0, sS, 0, 64, 3);
  // V[b] = Wv . Hn + v_b                 [512,1024]   T=32 tiles (4x8), nbx=8
  gemm_nt<u16><<<dim3(16 * 32), 256, 0, stream>>>(wv, hn, vv, v_b, nullptr, nullptr,
                                                  512, 512, 512, 1024, 0, sHN, sHN, 0, 32, 3);
  // S[b] = Q'^T . K                      [1024,1024]  T=64 tiles (8x8), nbx=8
  gemm_nt<u16><<<dim3(16 * 64), 256, 0, stream>>>(qkt, qkt + 512, Sb, nullptr, nullptr, nullptr,
                                                  512, 1024, 1024, 1024, sS, sS, sS, 0, 64, 3);
  softmax_kernel<<<4096, 256, 0, stream>>>(Sb);
  // O^T[b] = P . V^T                     [1024,512]   T=32 tiles (8x4), nbx=4
  gemm_nt<u16><<<dim3(16 * 32), 256, 0, stream>>>(Sb, vv, ot, nullptr, nullptr, nullptr,
                                                  1024, 1024, 1024, 512, sS, sHN, sHN, 0, 32, 2);
  // out[b] = Wp . O + p_b + x            [512,1024] f32  T=32 tiles (4x8), nbx=8
  gemm_nt<float><<<dim3(16 * 32), 256, 0, stream>>>(wp, ot, out, p_b, nullptr, x,
                                                    512, 512, 512, 1024, 0, sHN, sHN, sHN, 32, 3);
}